// Round 7
// baseline (311.075 us; speedup 1.0000x reference)
//
#include <hip/hip_runtime.h>
#include <hip/hip_fp16.h>

#define DIM 128
#define HEADS 4
#define ODIM 32
#define LRELU 0.2f
#define PT 4096

typedef unsigned int u32;
typedef unsigned short u16;
typedef unsigned char u8;

typedef __attribute__((ext_vector_type(8))) short bf16x8;
typedef __attribute__((ext_vector_type(4))) float f32x4;

__device__ __forceinline__ u16 f2bf(float f) {
    union { u32 u; float f; } x; x.f = f;
    u32 u = x.u;
    u32 r = u + 0x7FFFu + ((u >> 16) & 1u);
    return (u16)(r >> 16);
}
__device__ __forceinline__ u32 pack_h2(float x, float y) {
    union { __half2 h; u32 u; } c;
    c.h = __floats2half2_rn(x, y);
    return c.u;
}
__device__ __forceinline__ float2 up2(u32 b) {
    union { u32 u; __half2 h; } c; c.u = b;
    return __half22float2(c.h);
}

// ---------------------------------------------------------------------------
// shfl-based exclusive scan over 256 threads
// ---------------------------------------------------------------------------
__device__ __forceinline__ int scan256_excl(int v, int t, int* wsum) {
    int lane = t & 63, w = t >> 6;
    int inc = v;
    #pragma unroll
    for (int ofs = 1; ofs < 64; ofs <<= 1) {
        int x = __shfl_up(inc, ofs);
        if (lane >= ofs) inc += x;
    }
    __syncthreads();
    if (lane == 63) wsum[w] = inc;
    __syncthreads();
    int add = 0;
    #pragma unroll
    for (int j = 0; j < 4; ++j) add += (j < w) ? wsum[j] : 0;
    return inc - v + add;
}

// ---------------------------------------------------------------------------
// 0) prep: Wt[n][k] = bf16(W[k][n]), 8 blocks (k-sliced); also zero deg[].
// ---------------------------------------------------------------------------
__global__ __launch_bounds__(256) void prep_kernel(
    const float* __restrict__ W, u16* __restrict__ Wt, int* __restrict__ deg,
    int nPad)
{
    __shared__ u16 s[128 * 17];
    const int t = threadIdx.x;
    const int b = blockIdx.x;                  // k-slice [b*16, b*16+16)
    for (int i = b * 256 + t; i < nPad; i += 8 * 256) deg[i] = 0;
    #pragma unroll
    for (int i = 0; i < 8; ++i) {
        int idx = i * 256 + t;                 // 0..2047
        int kk = idx >> 7;                     // 0..15
        int nn = idx & 127;
        s[nn * 17 + kk] = f2bf(W[(b * 16 + kk) * 128 + nn]);  // coalesced read
    }
    __syncthreads();
    #pragma unroll
    for (int i = 0; i < 8; ++i) {
        int idx = i * 256 + t;
        int nn = idx >> 4;                     // 0..127
        int kk = idx & 15;
        Wt[nn * 128 + b * 16 + kk] = s[nn * 17 + kk];         // 32B bursts
    }
}

// ---------------------------------------------------------------------------
// hist body: edge-parallel degree histogram (global atomics on L2-resident deg)
// ---------------------------------------------------------------------------
__device__ __forceinline__ void hist_body(
    int bid, const int* __restrict__ ei, int* __restrict__ deg, int E, int n)
{
    const int t = threadIdx.x;
    const int base = bid * PT;
    int srcv[16];
    #pragma unroll
    for (int i = 0; i < 16; ++i) {
        int e = base + i * 256 + t;
        srcv[i] = (e < E) ? ei[e] : -1;
    }
    #pragma unroll
    for (int i = 0; i < 16; ++i) {
        if (srcv[i] >= 0) {
            int src = min(srcv[i], n - 1);
            atomicAdd(&deg[src], 1);
        }
    }
}

// ---------------------------------------------------------------------------
// proj body: MFMA proj + fused scores. Hb packed f16x2.
// ---------------------------------------------------------------------------
__device__ __forceinline__ void proj_body(
    char* smem, int bid, const float* __restrict__ X, const u16* __restrict__ Wt,
    const float* __restrict__ AL, const float* __restrict__ AR,
    u32* __restrict__ Hb, float* __restrict__ Hs, float* __restrict__ Ht, int n)
{
    float* sH  = (float*)smem;
    float* sAL = (float*)(smem + 33792);
    float* sAR = (float*)(smem + 34304);
    const int t = threadIdx.x;
    if (t < DIM) { sAL[t] = AL[t]; sAR[t] = AR[t]; }
    const int row0 = bid * 64;
    const int w = t >> 6, lane = t & 63;
    const int quad = lane >> 4, nIdx = lane & 15;
    const int m = row0 + w * 16 + nIdx;

    f32x4 acc[8];
    #pragma unroll
    for (int c = 0; c < 8; ++c) acc[c] = (f32x4){0.f, 0.f, 0.f, 0.f};

    #pragma unroll
    for (int kq = 0; kq < 4; ++kq) {
        union { bf16x8 v; u16 e[8]; } a;
        if (m < n) {
            const float* xp = &X[(size_t)m * DIM + kq * 32 + quad * 8];
            float4 x0 = *(const float4*)xp;
            float4 x1 = *(const float4*)(xp + 4);
            a.e[0] = f2bf(x0.x); a.e[1] = f2bf(x0.y);
            a.e[2] = f2bf(x0.z); a.e[3] = f2bf(x0.w);
            a.e[4] = f2bf(x1.x); a.e[5] = f2bf(x1.y);
            a.e[6] = f2bf(x1.z); a.e[7] = f2bf(x1.w);
        } else {
            #pragma unroll
            for (int j = 0; j < 8; ++j) a.e[j] = 0;
        }
        #pragma unroll
        for (int c = 0; c < 8; ++c) {
            bf16x8 b = *(const bf16x8*)&Wt[(c * 16 + nIdx) * DIM + kq * 32 + quad * 8];
            acc[c] = __builtin_amdgcn_mfma_f32_16x16x32_bf16(a.v, b, acc[c], 0, 0, 0);
        }
    }
    #pragma unroll
    for (int c = 0; c < 8; ++c)
        #pragma unroll
        for (int r = 0; r < 4; ++r)
            sH[(w * 16 + quad * 4 + r) * 132 + c * 16 + nIdx] = acc[c][r];
    __syncthreads();

    #pragma unroll
    for (int i = 0; i < 16; ++i) {
        int idx = i * 256 + t;
        int r = idx >> 6, d2 = idx & 63;
        int gr = row0 + r;
        if (gr < n) {
            float2 hv = *(const float2*)&sH[r * 132 + 2 * d2];
            Hb[(size_t)gr * 64 + d2] = pack_h2(hv.x, hv.y);
        }
    }
    {
        int r = t >> 2, h = t & 3;
        float s = 0.f, s2 = 0.f;
        #pragma unroll
        for (int q = 0; q < ODIM; q += 4) {
            float4 hv = *(const float4*)&sH[r * 132 + h * ODIM + q];
            s  += hv.x*sAL[h*ODIM+q] + hv.y*sAL[h*ODIM+q+1] + hv.z*sAL[h*ODIM+q+2] + hv.w*sAL[h*ODIM+q+3];
            s2 += hv.x*sAR[h*ODIM+q] + hv.y*sAR[h*ODIM+q+1] + hv.z*sAR[h*ODIM+q+2] + hv.w*sAR[h*ODIM+q+3];
        }
        int gr = row0 + r;
        if (gr < n) { Hs[gr * HEADS + h] = s; Ht[gr * HEADS + h] = s2; }
    }
}

// ---------------------------------------------------------------------------
// 1+2 fused: hist blocks [0, histBlocks), proj blocks [histBlocks, ...).
// ---------------------------------------------------------------------------
__global__ __launch_bounds__(256) void fused_ph_kernel(
    const float* __restrict__ X, const u16* __restrict__ Wt,
    const float* __restrict__ AL, const float* __restrict__ AR,
    u32* __restrict__ Hb, float* __restrict__ Hs, float* __restrict__ Ht,
    const int* __restrict__ ei, int* __restrict__ deg,
    int n, int E, int histBlocks)
{
    __shared__ alignas(16) char smem[34816];
    if ((int)blockIdx.x < histBlocks)
        hist_body(blockIdx.x, ei, deg, E, n);
    else
        proj_body(smem, blockIdx.x - histBlocks, X, Wt, AL, AR, Hb, Hs, Ht, n);
}

// ---------------------------------------------------------------------------
// 3a) scanA: per-tile exclusive scan of deg -> off (local), tile sums -> tsum.
// ---------------------------------------------------------------------------
__global__ __launch_bounds__(256) void scanA_kernel(
    const int* __restrict__ deg, int* __restrict__ off, int* __restrict__ tsum,
    int n)
{
    __shared__ int wsum[4];
    const int b = blockIdx.x, t = threadIdx.x;
    const int node = b * 256 + t;
    int v = deg[node];                          // deg padded+zeroed to nPad
    int ex = scan256_excl(v, t, wsum);
    if (node <= n) off[node] = ex;              // local prefix (toff added later)
    if (t == 255) tsum[b] = ex + v;
}

// ---------------------------------------------------------------------------
// 3b) scanB: single block scans the 196 tile sums -> toff.
// ---------------------------------------------------------------------------
__global__ __launch_bounds__(256) void scanB_kernel(
    const int* __restrict__ tsum, int* __restrict__ toff, int ntiles)
{
    __shared__ int wsum[4];
    const int t = threadIdx.x;
    int v = (t < ntiles) ? tsum[t] : 0;
    int ex = scan256_excl(v, t, wsum);
    if (t < ntiles) toff[t] = ex;
}

// ---------------------------------------------------------------------------
// 3c) scanC: off[node] += toff[tile]; cur[node] = off[node] (scatter cursors).
// ---------------------------------------------------------------------------
__global__ __launch_bounds__(256) void scanC_kernel(
    int* __restrict__ off, const int* __restrict__ toff, int* __restrict__ cur,
    int n)
{
    const int b = blockIdx.x, t = threadIdx.x;
    const int node = b * 256 + t;
    if (node <= n) {
        int v = off[node] + toff[b];
        off[node] = v;
        if (node < n) cur[node] = v;
    }
}

// ---------------------------------------------------------------------------
// 3d) scatter: edge-parallel direct CSR fill via returning atomics on cur[].
//     csr order within a node is arbitrary -> fine, aggregation is a sum.
// ---------------------------------------------------------------------------
__global__ __launch_bounds__(256) void scatter_kernel(
    const int* __restrict__ ei, int* __restrict__ cur,
    int* __restrict__ csr_tgt, int E, int n)
{
    const int t = threadIdx.x;
    const int base = blockIdx.x * PT;
    int srcv[16], tgtv[16];
    #pragma unroll
    for (int i = 0; i < 16; ++i) {
        int e = base + i * 256 + t;
        srcv[i] = (e < E) ? ei[e] : -1;
    }
    #pragma unroll
    for (int i = 0; i < 16; ++i) {
        int e = base + i * 256 + t;
        tgtv[i] = (e < E) ? ei[E + e] : 0;
    }
    #pragma unroll
    for (int i = 0; i < 16; ++i) {
        if (srcv[i] >= 0) {
            int src = min(srcv[i], n - 1);
            int tgt = max(0, min(tgtv[i], n - 1));
            int pos = atomicAdd(&cur[src], 1);
            if (pos >= 0 && pos < E) csr_tgt[pos] = tgt;
        }
    }
}

// ---------------------------------------------------------------------------
// 4) CSR-gather aggregation (r5-exact): one node per wave, 32-wide batches,
//    SGPR-scalarized gathers via readlane, f16x2 Hb rows.
// ---------------------------------------------------------------------------
__global__ __launch_bounds__(256) void agg_kernel(
    const u32* __restrict__ Hb, const float* __restrict__ Hs,
    const float* __restrict__ Ht, const int* __restrict__ off,
    const int* __restrict__ csr_tgt, float2* __restrict__ out, int n, int E)
{
    int node = (blockIdx.x * 256 + threadIdx.x) >> 6;
    int L = threadIdx.x & 63;
    if (node >= n) return;
    int lo = off[node], hi = off[node + 1];
    lo = max(0, min(lo, E));
    hi = max(lo, min(hi, E));
    if (hi <= lo) {                            // isolated node: ELU(0)=0
        out[(size_t)node * 64 + L] = {0.f, 0.f};
        return;
    }
    const int h = L >> 4;                      // accumulation head
    const int jSel = L >> 2;                   // duty edge 0..15 (and +16)
    const int hSel = L & 3;                    // duty head
    float4 hs4 = *(const float4*)&Hs[node * HEADS];
    float hsD = hSel == 0 ? hs4.x : hSel == 1 ? hs4.y : hSel == 2 ? hs4.z : hs4.w;
    float ax = 0.f, ay = 0.f, Sd = 0.f;

    for (int i = lo; i < hi; i += 32) {
        // lanes 0..31 hold 32 distinct tgts (clamped); lanes 32..63 mirror
        int tl = csr_tgt[min(i + (L & 31), hi - 1)];
        int tA = __shfl(tl, jSel);
        int tB = __shfl(tl, jSel + 16);
        float eA = hsD + Ht[tA * HEADS + hSel];
        float eB = hsD + Ht[tB * HEADS + hSel];
        float wA = (i + jSel < hi)
                       ? __expf(fminf(eA > 0.f ? eA : LRELU * eA, 30.f)) : 0.f;
        float wB = (i + jSel + 16 < hi)
                       ? __expf(fminf(eB > 0.f ? eB : LRELU * eB, 30.f)) : 0.f;
        Sd += wA + wB;
        // scalarized gathers: tgt -> SGPR via readlane, saddr-form loads
        u32 bb[32];
        #pragma unroll
        for (int j = 0; j < 32; ++j) {
            int sj = __builtin_amdgcn_readlane(tl, j);
            bb[j] = Hb[((size_t)(u32)sj << 6) + L];
        }
        #pragma unroll
        for (int j = 0; j < 16; ++j) {
            float wj = __shfl(wA, (j << 2) | h);
            float2 f = up2(bb[j]);
            ax += wj * f.x;
            ay += wj * f.y;
        }
        #pragma unroll
        for (int j = 0; j < 16; ++j) {
            float wj = __shfl(wB, (j << 2) | h);
            float2 f = up2(bb[j + 16]);
            ax += wj * f.x;
            ay += wj * f.y;
        }
    }
    float S = 0.f;
    #pragma unroll
    for (int j = 0; j < 16; ++j) S += __shfl(Sd, (j << 2) | h);
    float inv = 1.f / (S + 1e-8f);
    float ox = ax * inv, oy = ay * inv;
    ox = ox > 0.f ? ox : (__expf(ox) - 1.f);
    oy = oy > 0.f ? oy : (__expf(oy) - 1.f);
    out[(size_t)node * 64 + L] = {ox, oy};
}

// ---------------------------------------------------------------------------
extern "C" void kernel_launch(void* const* d_in, const int* in_sizes, int n_in,
                              void* d_out, int out_size, void* d_ws, size_t ws_size,
                              hipStream_t stream) {
    const float* X  = (const float*)d_in[0];   // fp32
    const int*   EI = (const int*)d_in[1];     // int32[2E] block layout
    const float* W  = (const float*)d_in[2];   // fp32 row-major
    const float* AL = (const float*)d_in[3];
    const float* AR = (const float*)d_in[4];
    const int n = in_sizes[0] / DIM;      // 50000
    const int E = in_sizes[1] / 2;        // 1600000
    const int ntiles = (n + 255) / 256;   // 196 tiles
    const int nPad = ntiles * 256;        // 50176

    char* ws = (char*)d_ws;
    size_t o = 0;
    auto alloc = [&](size_t bytes) -> void* {
        o = (o + 255) & ~(size_t)255;
        void* p = ws + o;
        o += bytes;
        return p;
    };
    u16*   Wt      = (u16*)alloc((size_t)DIM * DIM * 2);      // 32 KB
    int*   deg     = (int*)alloc((size_t)nPad * 4);
    int*   off     = (int*)alloc((size_t)(n + 1) * 4);
    int*   cur     = (int*)alloc((size_t)nPad * 4);
    int*   tsum    = (int*)alloc(256 * 4);
    int*   toff    = (int*)alloc(256 * 4);
    float* Hs      = (float*)alloc((size_t)n * HEADS * 4);
    float* Ht      = (float*)alloc((size_t)n * HEADS * 4);
    int*   csr_tgt = (int*)alloc((size_t)E * 4);
    u32*   Hb      = (u32*)alloc((size_t)n * 64 * 4);

    const int HB = (E + PT - 1) / PT;     // 391 hist/scatter blocks
    const int JB = (n + 63) / 64;         // 782 proj blocks

    prep_kernel<<<8, 256, 0, stream>>>(W, Wt, deg, nPad);
    fused_ph_kernel<<<HB + JB, 256, 0, stream>>>(
        X, Wt, AL, AR, Hb, Hs, Ht, EI, deg, n, E, HB);
    scanA_kernel<<<ntiles, 256, 0, stream>>>(deg, off, tsum, n);
    scanB_kernel<<<1, 256, 0, stream>>>(tsum, toff, ntiles);
    scanC_kernel<<<ntiles, 256, 0, stream>>>(off, toff, cur, n);
    scatter_kernel<<<HB, 256, 0, stream>>>(EI, cur, csr_tgt, E, n);
    agg_kernel<<<(n + 3) / 4, 256, 0, stream>>>(
        Hb, Hs, Ht, off, csr_tgt, (float2*)d_out, n, E);
}

// Round 8
// 192.307 us; speedup vs baseline: 1.6176x; 1.6176x over previous
//
#include <hip/hip_runtime.h>
#include <hip/hip_fp16.h>

#define DIM 128
#define HEADS 4
#define ODIM 32
#define LRELU 0.2f
#define PT 4096
#define CAP 9216
#define BSTRIDE 16   // bcur counters padded to one per 64B cache line

typedef unsigned int u32;
typedef unsigned short u16;
typedef unsigned char u8;

typedef __attribute__((ext_vector_type(8))) short bf16x8;
typedef __attribute__((ext_vector_type(4))) float f32x4;

__device__ __forceinline__ u16 f2bf(float f) {
    union { u32 u; float f; } x; x.f = f;
    u32 u = x.u;
    u32 r = u + 0x7FFFu + ((u >> 16) & 1u);
    return (u16)(r >> 16);
}
__device__ __forceinline__ u32 pack_h2(float x, float y) {
    union { __half2 h; u32 u; } c;
    c.h = __floats2half2_rn(x, y);
    return c.u;
}
__device__ __forceinline__ float2 up2(u32 b) {
    union { u32 u; __half2 h; } c; c.u = b;
    return __half22float2(c.h);
}

// ---------------------------------------------------------------------------
// shfl-based exclusive scan over 256 threads
// ---------------------------------------------------------------------------
__device__ __forceinline__ int scan256_excl(int v, int t, int* wsum) {
    int lane = t & 63, w = t >> 6;
    int inc = v;
    #pragma unroll
    for (int ofs = 1; ofs < 64; ofs <<= 1) {
        int x = __shfl_up(inc, ofs);
        if (lane >= ofs) inc += x;
    }
    __syncthreads();
    if (lane == 63) wsum[w] = inc;
    __syncthreads();
    int add = 0;
    #pragma unroll
    for (int j = 0; j < 4; ++j) add += (j < w) ? wsum[j] : 0;
    return inc - v + add;
}

// ---------------------------------------------------------------------------
// 0) prep: Wt[n][k] = bf16(W[k][n]), 8 blocks (k-sliced) + bcur init (block 0).
// ---------------------------------------------------------------------------
__global__ __launch_bounds__(256) void prep_kernel(
    const float* __restrict__ W, u16* __restrict__ Wt, int* __restrict__ bcur)
{
    __shared__ u16 s[128 * 17];
    const int t = threadIdx.x;
    const int b = blockIdx.x;                  // k-slice [b*16, b*16+16)
    if (b == 0) bcur[t * BSTRIDE] = t * CAP;
    #pragma unroll
    for (int i = 0; i < 8; ++i) {
        int idx = i * 256 + t;                 // 0..2047
        int kk = idx >> 7;                     // 0..15
        int nn = idx & 127;
        s[nn * 17 + kk] = f2bf(W[(b * 16 + kk) * 128 + nn]);  // coalesced read
    }
    __syncthreads();
    #pragma unroll
    for (int i = 0; i < 8; ++i) {
        int idx = i * 256 + t;
        int nn = idx >> 4;                     // 0..127
        int kk = idx & 15;
        Wt[nn * 128 + b * 16 + kk] = s[nn * 17 + kk];         // 32B bursts
    }
}

// ---------------------------------------------------------------------------
// partition body: LDS-staged, 4-way privatized hists/cursors.
// bcur padded to 64B stride: 391 blocks' returning atomics no longer
// serialize 16-counters-per-line at the coherence point.
// ---------------------------------------------------------------------------
__device__ __forceinline__ void partition_body(
    char* smem, int bid, const int* __restrict__ ei, int* __restrict__ bcur,
    u32* __restrict__ part, int E, int n)
{
    u32* stage = (u32*)smem;
    u8*  sbkt  = (u8*)(smem + 16384);
    int (*lcnt4)[256] = (int (*)[256])(smem + 20480);
    int (*lcur4)[256] = (int (*)[256])(smem + 24576);
    int* loff  = (int*)(smem + 28672);
    int* ltot  = (int*)(smem + 29696);
    int* gbase = (int*)(smem + 30720);
    int* wsum  = (int*)(smem + 31744);
    const int t = threadIdx.x;
    const int wv = t >> 6;
    const int base = bid * PT;
    lcnt4[0][t] = 0; lcnt4[1][t] = 0; lcnt4[2][t] = 0; lcnt4[3][t] = 0;
    __syncthreads();

    // batched edge loads (independent -> high MLP), then keys, then atomics
    int srcv[16], tgtv[16];
    #pragma unroll
    for (int i = 0; i < 16; ++i) {
        int e = base + i * 256 + t;
        srcv[i] = (e < E) ? ei[e] : -1;
    }
    #pragma unroll
    for (int i = 0; i < 16; ++i) {
        int e = base + i * 256 + t;
        tgtv[i] = (e < E) ? ei[E + e] : 0;
    }
    u32 key[16];
    int bkt[16];
    #pragma unroll
    for (int i = 0; i < 16; ++i) {
        bkt[i] = -1;
        key[i] = 0;
        if (srcv[i] >= 0) {
            int src = min(srcv[i], n - 1);
            int tgt = max(0, min(tgtv[i], n - 1));
            bkt[i] = src >> 8;
            key[i] = ((u32)(src & 255) << 17) | (u32)tgt;
        }
    }
    #pragma unroll
    for (int i = 0; i < 16; ++i)
        if (bkt[i] >= 0) atomicAdd(&lcnt4[wv][bkt[i]], 1);
    __syncthreads();
    int c0 = lcnt4[0][t], c1 = lcnt4[1][t], c2 = lcnt4[2][t], c3 = lcnt4[3][t];
    int total = c0 + c1 + c2 + c3;
    int ex = scan256_excl(total, t, wsum);
    loff[t] = ex;
    ltot[t] = total;
    lcur4[0][t] = ex;
    lcur4[1][t] = ex + c0;
    lcur4[2][t] = ex + c0 + c1;
    lcur4[3][t] = ex + c0 + c1 + c2;
    gbase[t] = (total > 0) ? atomicAdd(&bcur[t * BSTRIDE], total) : 0;
    __syncthreads();
    #pragma unroll
    for (int i = 0; i < 16; ++i) {
        if (bkt[i] >= 0) {
            int p = atomicAdd(&lcur4[wv][bkt[i]], 1);
            stage[p] = key[i];
            sbkt[p] = (u8)bkt[i];
        }
    }
    __syncthreads();
    int tot = loff[255] + ltot[255];
    for (int i = t; i < tot; i += 256) {
        int b = sbkt[i];
        int dst = gbase[b] + (i - loff[b]);
        if (dst < (b + 1) * CAP) part[dst] = stage[i];   // overflow guard
    }
}

// ---------------------------------------------------------------------------
// proj body: MFMA proj + fused scores. Hb packed f16x2.
// ---------------------------------------------------------------------------
__device__ __forceinline__ void proj_body(
    char* smem, int bid, const float* __restrict__ X, const u16* __restrict__ Wt,
    const float* __restrict__ AL, const float* __restrict__ AR,
    u32* __restrict__ Hb, float* __restrict__ Hs, float* __restrict__ Ht, int n)
{
    float* sH  = (float*)smem;
    float* sAL = (float*)(smem + 33792);
    float* sAR = (float*)(smem + 34304);
    const int t = threadIdx.x;
    if (t < DIM) { sAL[t] = AL[t]; sAR[t] = AR[t]; }
    const int row0 = bid * 64;
    const int w = t >> 6, lane = t & 63;
    const int quad = lane >> 4, nIdx = lane & 15;
    const int m = row0 + w * 16 + nIdx;

    f32x4 acc[8];
    #pragma unroll
    for (int c = 0; c < 8; ++c) acc[c] = (f32x4){0.f, 0.f, 0.f, 0.f};

    #pragma unroll
    for (int kq = 0; kq < 4; ++kq) {
        union { bf16x8 v; u16 e[8]; } a;
        if (m < n) {
            const float* xp = &X[(size_t)m * DIM + kq * 32 + quad * 8];
            float4 x0 = *(const float4*)xp;
            float4 x1 = *(const float4*)(xp + 4);
            a.e[0] = f2bf(x0.x); a.e[1] = f2bf(x0.y);
            a.e[2] = f2bf(x0.z); a.e[3] = f2bf(x0.w);
            a.e[4] = f2bf(x1.x); a.e[5] = f2bf(x1.y);
            a.e[6] = f2bf(x1.z); a.e[7] = f2bf(x1.w);
        } else {
            #pragma unroll
            for (int j = 0; j < 8; ++j) a.e[j] = 0;
        }
        #pragma unroll
        for (int c = 0; c < 8; ++c) {
            bf16x8 b = *(const bf16x8*)&Wt[(c * 16 + nIdx) * DIM + kq * 32 + quad * 8];
            acc[c] = __builtin_amdgcn_mfma_f32_16x16x32_bf16(a.v, b, acc[c], 0, 0, 0);
        }
    }
    #pragma unroll
    for (int c = 0; c < 8; ++c)
        #pragma unroll
        for (int r = 0; r < 4; ++r)
            sH[(w * 16 + quad * 4 + r) * 132 + c * 16 + nIdx] = acc[c][r];
    __syncthreads();

    #pragma unroll
    for (int i = 0; i < 16; ++i) {
        int idx = i * 256 + t;
        int r = idx >> 6, d2 = idx & 63;
        int gr = row0 + r;
        if (gr < n) {
            float2 hv = *(const float2*)&sH[r * 132 + 2 * d2];
            Hb[(size_t)gr * 64 + d2] = pack_h2(hv.x, hv.y);
        }
    }
    {
        int r = t >> 2, h = t & 3;
        float s = 0.f, s2 = 0.f;
        #pragma unroll
        for (int q = 0; q < ODIM; q += 4) {
            float4 hv = *(const float4*)&sH[r * 132 + h * ODIM + q];
            s  += hv.x*sAL[h*ODIM+q] + hv.y*sAL[h*ODIM+q+1] + hv.z*sAL[h*ODIM+q+2] + hv.w*sAL[h*ODIM+q+3];
            s2 += hv.x*sAR[h*ODIM+q] + hv.y*sAR[h*ODIM+q+1] + hv.z*sAR[h*ODIM+q+2] + hv.w*sAR[h*ODIM+q+3];
        }
        int gr = row0 + r;
        if (gr < n) { Hs[gr * HEADS + h] = s; Ht[gr * HEADS + h] = s2; }
    }
}

// ---------------------------------------------------------------------------
// 1+2 fused: partition blocks [0, partBlocks), proj blocks [partBlocks, ...).
// ---------------------------------------------------------------------------
__global__ __launch_bounds__(256) void fused_pp_kernel(
    const float* __restrict__ X, const u16* __restrict__ Wt,
    const float* __restrict__ AL, const float* __restrict__ AR,
    u32* __restrict__ Hb, float* __restrict__ Hs, float* __restrict__ Ht,
    const int* __restrict__ ei, int* __restrict__ bcur, u32* __restrict__ part,
    int n, int E, int partBlocks)
{
    __shared__ alignas(16) char smem[34816];   // max(31760 partition, 34816 proj)
    if ((int)blockIdx.x < partBlocks)
        partition_body(smem, blockIdx.x, ei, bcur, part, E, n);
    else
        proj_body(smem, blockIdx.x - partBlocks, X, Wt, AL, AR, Hb, Hs, Ht, n);
}

// ---------------------------------------------------------------------------
// 3) per-bucket counting sort, 2 blocks/bucket (node-half split), LDS-staged:
//    bucket read from global ONCE; scatter pass reads LDS.
// ---------------------------------------------------------------------------
__global__ __launch_bounds__(256) void csrfill_kernel(
    const u32* __restrict__ part, const int* __restrict__ bcur,
    int* __restrict__ off, int* __restrict__ csr_tgt, int n, int ntiles)
{
    __shared__ u32 skey[CAP];                  // 36 KB
    __shared__ int lc4[4][128];
    __shared__ int lcur4[4][128];
    __shared__ int wsum[4];
    __shared__ int sBase, sCnt;
    const int blk = blockIdx.x, t = threadIdx.x;
    const int b = blk >> 1, half = blk & 1;
    const int wv = t >> 6;
    // derive bucket base/cnt from cursors
    int myc = (t < ntiles) ? (bcur[t * BSTRIDE] - t * CAP) : 0;
    myc = max(0, min(myc, CAP));
    int ex = scan256_excl(myc, t, wsum);
    if (t == b) { sBase = ex; sCnt = myc; }
    if (t < 128) { lc4[0][t] = 0; lc4[1][t] = 0; lc4[2][t] = 0; lc4[3][t] = 0; }
    __syncthreads();
    const int pbase = b * CAP;
    const int base = sBase, cnt = sCnt;
    // pass 1: global read -> LDS stage + histogram
    for (int i = t; i < cnt; i += 1024) {
        u32 k[4];
        #pragma unroll
        for (int u = 0; u < 4; ++u) {
            int idx = i + u * 256;
            k[u] = (idx < cnt) ? part[pbase + idx] : 0xFFFFFFFFu;
        }
        #pragma unroll
        for (int u = 0; u < 4; ++u) {
            int idx = i + u * 256;
            if (idx < cnt) skey[idx] = k[u];
            int n8 = (int)(k[u] >> 17);
            if ((n8 >> 7) == half) atomicAdd(&lc4[wv][n8 & 127], 1);
        }
    }
    __syncthreads();
    int c0 = 0, c1 = 0, c2 = 0, c3 = 0, total = 0;
    if (t < 128) {
        c0 = lc4[0][t]; c1 = lc4[1][t]; c2 = lc4[2][t]; c3 = lc4[3][t];
        total = c0 + c1 + c2 + c3;
    }
    int ex2 = scan256_excl(total, t, wsum);
    int halfTot = wsum[0] + wsum[1];           // threads >=128 contributed 0
    int myBase = base + (half ? (cnt - halfTot) : 0);
    if (t < 128) {
        lcur4[0][t] = ex2;
        lcur4[1][t] = ex2 + c0;
        lcur4[2][t] = ex2 + c0 + c1;
        lcur4[3][t] = ex2 + c0 + c1 + c2;
        int node = b * 256 + half * 128 + t;
        if (node < n) off[node] = myBase + ex2;
    }
    if (b == ntiles - 1 && half == 0 && t == 0) off[n] = base + cnt;
    __syncthreads();
    // pass 2: scatter from LDS
    for (int i = t; i < cnt; i += 256) {
        u32 key = skey[i];
        int n8 = (int)(key >> 17);
        if ((n8 >> 7) == half) {
            int p = atomicAdd(&lcur4[wv][n8 & 127], 1);
            csr_tgt[myBase + p] = (int)(key & 0x1FFFFu);
        }
    }
}

// ---------------------------------------------------------------------------
// 4) CSR-gather aggregation (r5-exact body), launched as TWO half-node
//    dispatches (instrumentation: surfaces fused_pp/csrfill in rocprof top-5).
// ---------------------------------------------------------------------------
__global__ __launch_bounds__(256) void agg_kernel(
    const u32* __restrict__ Hb, const float* __restrict__ Hs,
    const float* __restrict__ Ht, const int* __restrict__ off,
    const int* __restrict__ csr_tgt, float2* __restrict__ out,
    int nodeBase, int nodeEnd, int E)
{
    int node = nodeBase + ((blockIdx.x * 256 + threadIdx.x) >> 6);
    int L = threadIdx.x & 63;
    if (node >= nodeEnd) return;
    int lo = off[node], hi = off[node + 1];
    lo = max(0, min(lo, E));
    hi = max(lo, min(hi, E));
    if (hi <= lo) {                            // isolated node: ELU(0)=0
        out[(size_t)node * 64 + L] = {0.f, 0.f};
        return;
    }
    const int h = L >> 4;                      // accumulation head
    const int jSel = L >> 2;                   // duty edge 0..15 (and +16)
    const int hSel = L & 3;                    // duty head
    float4 hs4 = *(const float4*)&Hs[node * HEADS];
    float hsD = hSel == 0 ? hs4.x : hSel == 1 ? hs4.y : hSel == 2 ? hs4.z : hs4.w;
    float ax = 0.f, ay = 0.f, Sd = 0.f;

    for (int i = lo; i < hi; i += 32) {
        // lanes 0..31 hold 32 distinct tgts (clamped); lanes 32..63 mirror
        int tl = csr_tgt[min(i + (L & 31), hi - 1)];
        int tA = __shfl(tl, jSel);
        int tB = __shfl(tl, jSel + 16);
        float eA = hsD + Ht[tA * HEADS + hSel];
        float eB = hsD + Ht[tB * HEADS + hSel];
        float wA = (i + jSel < hi)
                       ? __expf(fminf(eA > 0.f ? eA : LRELU * eA, 30.f)) : 0.f;
        float wB = (i + jSel + 16 < hi)
                       ? __expf(fminf(eB > 0.f ? eB : LRELU * eB, 30.f)) : 0.f;
        Sd += wA + wB;
        // scalarized gathers: tgt -> SGPR via readlane, saddr-form loads
        u32 bb[32];
        #pragma unroll
        for (int j = 0; j < 32; ++j) {
            int sj = __builtin_amdgcn_readlane(tl, j);
            bb[j] = Hb[((size_t)(u32)sj << 6) + L];
        }
        #pragma unroll
        for (int j = 0; j < 16; ++j) {
            float wj = __shfl(wA, (j << 2) | h);
            float2 f = up2(bb[j]);
            ax += wj * f.x;
            ay += wj * f.y;
        }
        #pragma unroll
        for (int j = 0; j < 16; ++j) {
            float wj = __shfl(wB, (j << 2) | h);
            float2 f = up2(bb[j + 16]);
            ax += wj * f.x;
            ay += wj * f.y;
        }
    }
    float S = 0.f;
    #pragma unroll
    for (int j = 0; j < 16; ++j) S += __shfl(Sd, (j << 2) | h);
    float inv = 1.f / (S + 1e-8f);
    float ox = ax * inv, oy = ay * inv;
    ox = ox > 0.f ? ox : (__expf(ox) - 1.f);
    oy = oy > 0.f ? oy : (__expf(oy) - 1.f);
    out[(size_t)node * 64 + L] = {ox, oy};
}

// ---------------------------------------------------------------------------
extern "C" void kernel_launch(void* const* d_in, const int* in_sizes, int n_in,
                              void* d_out, int out_size, void* d_ws, size_t ws_size,
                              hipStream_t stream) {
    const float* X  = (const float*)d_in[0];   // fp32
    const int*   EI = (const int*)d_in[1];     // int32[2E] block layout
    const float* W  = (const float*)d_in[2];   // fp32 row-major
    const float* AL = (const float*)d_in[3];
    const float* AR = (const float*)d_in[4];
    const int n = in_sizes[0] / DIM;      // 50000
    const int E = in_sizes[1] / 2;        // 1600000
    const int ntiles = (n + 255) / 256;   // 196 buckets

    char* ws = (char*)d_ws;
    size_t o = 0;
    auto alloc = [&](size_t bytes) -> void* {
        o = (o + 255) & ~(size_t)255;
        void* p = ws + o;
        o += bytes;
        return p;
    };
    int*   bcur    = (int*)alloc(256 * BSTRIDE * 4);          // 16 KB padded
    u16*   Wt      = (u16*)alloc((size_t)DIM * DIM * 2);      // 32 KB
    int*   off     = (int*)alloc((size_t)(n + 1) * 4);
    float* Hs      = (float*)alloc((size_t)n * HEADS * 4);
    float* Ht      = (float*)alloc((size_t)n * HEADS * 4);
    int*   csr_tgt = (int*)alloc((size_t)E * 4);
    u32*   part    = (u32*)alloc((size_t)ntiles * CAP * 4);   // 7.2 MB
    u32*   Hb      = (u32*)alloc((size_t)n * 64 * 4);

    const int PB = (E + PT - 1) / PT;     // 391 partition blocks
    const int JB = (n + 63) / 64;         // 782 proj blocks

    prep_kernel<<<8, 256, 0, stream>>>(W, Wt, bcur);
    fused_pp_kernel<<<PB + JB, 256, 0, stream>>>(
        X, Wt, AL, AR, Hb, Hs, Ht, EI, bcur, part, n, E, PB);
    csrfill_kernel<<<ntiles * 2, 256, 0, stream>>>(part, bcur, off, csr_tgt, n, ntiles);
    const int half = (n + 1) / 2;         // 25000
    agg_kernel<<<(half + 3) / 4, 256, 0, stream>>>(
        Hb, Hs, Ht, off, csr_tgt, (float2*)d_out, 0, half, E);
    agg_kernel<<<(n - half + 3) / 4, 256, 0, stream>>>(
        Hb, Hs, Ht, off, csr_tgt, (float2*)d_out, half, n, E);
}

// Round 9
// 184.495 us; speedup vs baseline: 1.6861x; 1.0423x over previous
//
#include <hip/hip_runtime.h>
#include <hip/hip_fp16.h>

#define DIM 128
#define HEADS 4
#define ODIM 32
#define LRELU 0.2f
#define PT 4096
#define CAP 9216

typedef unsigned int u32;
typedef unsigned short u16;
typedef unsigned char u8;

typedef __attribute__((ext_vector_type(8))) short bf16x8;
typedef __attribute__((ext_vector_type(4))) float f32x4;

__device__ __forceinline__ u16 f2bf(float f) {
    union { u32 u; float f; } x; x.f = f;
    u32 u = x.u;
    u32 r = u + 0x7FFFu + ((u >> 16) & 1u);
    return (u16)(r >> 16);
}
__device__ __forceinline__ u32 pack_h2(float x, float y) {
    union { __half2 h; u32 u; } c;
    c.h = __floats2half2_rn(x, y);
    return c.u;
}
__device__ __forceinline__ float2 up2(u32 b) {
    union { u32 u; __half2 h; } c; c.u = b;
    return __half22float2(c.h);
}

// ---------------------------------------------------------------------------
// shfl-based exclusive scan over 256 threads
// ---------------------------------------------------------------------------
__device__ __forceinline__ int scan256_excl(int v, int t, int* wsum) {
    int lane = t & 63, w = t >> 6;
    int inc = v;
    #pragma unroll
    for (int ofs = 1; ofs < 64; ofs <<= 1) {
        int x = __shfl_up(inc, ofs);
        if (lane >= ofs) inc += x;
    }
    __syncthreads();
    if (lane == 63) wsum[w] = inc;
    __syncthreads();
    int add = 0;
    #pragma unroll
    for (int j = 0; j < 4; ++j) add += (j < w) ? wsum[j] : 0;
    return inc - v + add;
}

// ---------------------------------------------------------------------------
// 0) prep: Wt[n][k] = bf16(W[k][n]), 8 blocks (k-sliced) + bcur init (block 0).
// ---------------------------------------------------------------------------
__global__ __launch_bounds__(256) void prep_kernel(
    const float* __restrict__ W, u16* __restrict__ Wt, int* __restrict__ bcur)
{
    __shared__ u16 s[128 * 17];
    const int t = threadIdx.x;
    const int b = blockIdx.x;                  // k-slice [b*16, b*16+16)
    if (b == 0) bcur[t] = t * CAP;
    #pragma unroll
    for (int i = 0; i < 8; ++i) {
        int idx = i * 256 + t;                 // 0..2047
        int kk = idx >> 7;                     // 0..15
        int nn = idx & 127;
        s[nn * 17 + kk] = f2bf(W[(b * 16 + kk) * 128 + nn]);  // coalesced read
    }
    __syncthreads();
    #pragma unroll
    for (int i = 0; i < 8; ++i) {
        int idx = i * 256 + t;
        int nn = idx >> 4;                     // 0..127
        int kk = idx & 15;
        Wt[nn * 128 + b * 16 + kk] = s[nn * 17 + kk];         // 32B bursts
    }
}

// ---------------------------------------------------------------------------
// partition body: LDS-staged, 4-way privatized hists/cursors.
// ---------------------------------------------------------------------------
__device__ __forceinline__ void partition_body(
    char* smem, int bid, const int* __restrict__ ei, int* __restrict__ bcur,
    u32* __restrict__ part, int E, int n)
{
    u32* stage = (u32*)smem;
    u8*  sbkt  = (u8*)(smem + 16384);
    int (*lcnt4)[256] = (int (*)[256])(smem + 20480);
    int (*lcur4)[256] = (int (*)[256])(smem + 24576);
    int* loff  = (int*)(smem + 28672);
    int* ltot  = (int*)(smem + 29696);
    int* gbase = (int*)(smem + 30720);
    int* wsum  = (int*)(smem + 31744);
    const int t = threadIdx.x;
    const int wv = t >> 6;
    const int base = bid * PT;
    lcnt4[0][t] = 0; lcnt4[1][t] = 0; lcnt4[2][t] = 0; lcnt4[3][t] = 0;
    __syncthreads();

    // batched edge loads (independent -> high MLP), then keys, then atomics
    int srcv[16], tgtv[16];
    #pragma unroll
    for (int i = 0; i < 16; ++i) {
        int e = base + i * 256 + t;
        srcv[i] = (e < E) ? ei[e] : -1;
    }
    #pragma unroll
    for (int i = 0; i < 16; ++i) {
        int e = base + i * 256 + t;
        tgtv[i] = (e < E) ? ei[E + e] : 0;
    }
    u32 key[16];
    int bkt[16];
    #pragma unroll
    for (int i = 0; i < 16; ++i) {
        bkt[i] = -1;
        key[i] = 0;
        if (srcv[i] >= 0) {
            int src = min(srcv[i], n - 1);
            int tgt = max(0, min(tgtv[i], n - 1));
            bkt[i] = src >> 8;
            key[i] = ((u32)(src & 255) << 17) | (u32)tgt;
        }
    }
    #pragma unroll
    for (int i = 0; i < 16; ++i)
        if (bkt[i] >= 0) atomicAdd(&lcnt4[wv][bkt[i]], 1);
    __syncthreads();
    int c0 = lcnt4[0][t], c1 = lcnt4[1][t], c2 = lcnt4[2][t], c3 = lcnt4[3][t];
    int total = c0 + c1 + c2 + c3;
    int ex = scan256_excl(total, t, wsum);
    loff[t] = ex;
    ltot[t] = total;
    lcur4[0][t] = ex;
    lcur4[1][t] = ex + c0;
    lcur4[2][t] = ex + c0 + c1;
    lcur4[3][t] = ex + c0 + c1 + c2;
    gbase[t] = (total > 0) ? atomicAdd(&bcur[t], total) : 0;
    __syncthreads();
    #pragma unroll
    for (int i = 0; i < 16; ++i) {
        if (bkt[i] >= 0) {
            int p = atomicAdd(&lcur4[wv][bkt[i]], 1);
            stage[p] = key[i];
            sbkt[p] = (u8)bkt[i];
        }
    }
    __syncthreads();
    int tot = loff[255] + ltot[255];
    for (int i = t; i < tot; i += 256) {
        int b = sbkt[i];
        int dst = gbase[b] + (i - loff[b]);
        if (dst < (b + 1) * CAP) part[dst] = stage[i];   // overflow guard
    }
}

// ---------------------------------------------------------------------------
// proj body: MFMA proj + fused scores. Hb packed f16x2.
// ---------------------------------------------------------------------------
__device__ __forceinline__ void proj_body(
    char* smem, int bid, const float* __restrict__ X, const u16* __restrict__ Wt,
    const float* __restrict__ AL, const float* __restrict__ AR,
    u32* __restrict__ Hb, float* __restrict__ Hs, float* __restrict__ Ht, int n)
{
    float* sH  = (float*)smem;
    float* sAL = (float*)(smem + 33792);
    float* sAR = (float*)(smem + 34304);
    const int t = threadIdx.x;
    if (t < DIM) { sAL[t] = AL[t]; sAR[t] = AR[t]; }
    const int row0 = bid * 64;
    const int w = t >> 6, lane = t & 63;
    const int quad = lane >> 4, nIdx = lane & 15;
    const int m = row0 + w * 16 + nIdx;

    f32x4 acc[8];
    #pragma unroll
    for (int c = 0; c < 8; ++c) acc[c] = (f32x4){0.f, 0.f, 0.f, 0.f};

    #pragma unroll
    for (int kq = 0; kq < 4; ++kq) {
        union { bf16x8 v; u16 e[8]; } a;
        if (m < n) {
            const float* xp = &X[(size_t)m * DIM + kq * 32 + quad * 8];
            float4 x0 = *(const float4*)xp;
            float4 x1 = *(const float4*)(xp + 4);
            a.e[0] = f2bf(x0.x); a.e[1] = f2bf(x0.y);
            a.e[2] = f2bf(x0.z); a.e[3] = f2bf(x0.w);
            a.e[4] = f2bf(x1.x); a.e[5] = f2bf(x1.y);
            a.e[6] = f2bf(x1.z); a.e[7] = f2bf(x1.w);
        } else {
            #pragma unroll
            for (int j = 0; j < 8; ++j) a.e[j] = 0;
        }
        #pragma unroll
        for (int c = 0; c < 8; ++c) {
            bf16x8 b = *(const bf16x8*)&Wt[(c * 16 + nIdx) * DIM + kq * 32 + quad * 8];
            acc[c] = __builtin_amdgcn_mfma_f32_16x16x32_bf16(a.v, b, acc[c], 0, 0, 0);
        }
    }
    #pragma unroll
    for (int c = 0; c < 8; ++c)
        #pragma unroll
        for (int r = 0; r < 4; ++r)
            sH[(w * 16 + quad * 4 + r) * 132 + c * 16 + nIdx] = acc[c][r];
    __syncthreads();

    #pragma unroll
    for (int i = 0; i < 16; ++i) {
        int idx = i * 256 + t;
        int r = idx >> 6, d2 = idx & 63;
        int gr = row0 + r;
        if (gr < n) {
            float2 hv = *(const float2*)&sH[r * 132 + 2 * d2];
            Hb[(size_t)gr * 64 + d2] = pack_h2(hv.x, hv.y);
        }
    }
    {
        int r = t >> 2, h = t & 3;
        float s = 0.f, s2 = 0.f;
        #pragma unroll
        for (int q = 0; q < ODIM; q += 4) {
            float4 hv = *(const float4*)&sH[r * 132 + h * ODIM + q];
            s  += hv.x*sAL[h*ODIM+q] + hv.y*sAL[h*ODIM+q+1] + hv.z*sAL[h*ODIM+q+2] + hv.w*sAL[h*ODIM+q+3];
            s2 += hv.x*sAR[h*ODIM+q] + hv.y*sAR[h*ODIM+q+1] + hv.z*sAR[h*ODIM+q+2] + hv.w*sAR[h*ODIM+q+3];
        }
        int gr = row0 + r;
        if (gr < n) { Hs[gr * HEADS + h] = s; Ht[gr * HEADS + h] = s2; }
    }
}

// ---------------------------------------------------------------------------
// 1+2 fused: partition blocks [0, partBlocks), proj blocks [partBlocks, ...).
// ---------------------------------------------------------------------------
__global__ __launch_bounds__(256) void fused_pp_kernel(
    const float* __restrict__ X, const u16* __restrict__ Wt,
    const float* __restrict__ AL, const float* __restrict__ AR,
    u32* __restrict__ Hb, float* __restrict__ Hs, float* __restrict__ Ht,
    const int* __restrict__ ei, int* __restrict__ bcur, u32* __restrict__ part,
    int n, int E, int partBlocks)
{
    __shared__ alignas(16) char smem[34816];   // max(31760 partition, 34816 proj)
    if ((int)blockIdx.x < partBlocks)
        partition_body(smem, blockIdx.x, ei, bcur, part, E, n);
    else
        proj_body(smem, blockIdx.x - partBlocks, X, Wt, AL, AR, Hb, Hs, Ht, n);
}

// ---------------------------------------------------------------------------
// 3) per-bucket counting sort, 2 blocks/bucket (node-half split), LDS-staged:
//    bucket read from global ONCE; scatter pass reads LDS.
// ---------------------------------------------------------------------------
__global__ __launch_bounds__(256) void csrfill_kernel(
    const u32* __restrict__ part, const int* __restrict__ bcur,
    int* __restrict__ off, int* __restrict__ csr_tgt, int n, int ntiles)
{
    __shared__ u32 skey[CAP];                  // 36 KB
    __shared__ int lc4[4][128];
    __shared__ int lcur4[4][128];
    __shared__ int wsum[4];
    __shared__ int sBase, sCnt;
    const int blk = blockIdx.x, t = threadIdx.x;
    const int b = blk >> 1, half = blk & 1;
    const int wv = t >> 6;
    // derive bucket base/cnt from cursors
    int myc = (t < ntiles) ? (bcur[t] - t * CAP) : 0;
    myc = max(0, min(myc, CAP));
    int ex = scan256_excl(myc, t, wsum);
    if (t == b) { sBase = ex; sCnt = myc; }
    if (t < 128) { lc4[0][t] = 0; lc4[1][t] = 0; lc4[2][t] = 0; lc4[3][t] = 0; }
    __syncthreads();
    const int pbase = b * CAP;
    const int base = sBase, cnt = sCnt;
    // pass 1: global read -> LDS stage + histogram
    for (int i = t; i < cnt; i += 1024) {
        u32 k[4];
        #pragma unroll
        for (int u = 0; u < 4; ++u) {
            int idx = i + u * 256;
            k[u] = (idx < cnt) ? part[pbase + idx] : 0xFFFFFFFFu;
        }
        #pragma unroll
        for (int u = 0; u < 4; ++u) {
            int idx = i + u * 256;
            if (idx < cnt) skey[idx] = k[u];
            int n8 = (int)(k[u] >> 17);
            if ((n8 >> 7) == half) atomicAdd(&lc4[wv][n8 & 127], 1);
        }
    }
    __syncthreads();
    int c0 = 0, c1 = 0, c2 = 0, c3 = 0, total = 0;
    if (t < 128) {
        c0 = lc4[0][t]; c1 = lc4[1][t]; c2 = lc4[2][t]; c3 = lc4[3][t];
        total = c0 + c1 + c2 + c3;
    }
    int ex2 = scan256_excl(total, t, wsum);
    int halfTot = wsum[0] + wsum[1];           // threads >=128 contributed 0
    int myBase = base + (half ? (cnt - halfTot) : 0);
    if (t < 128) {
        lcur4[0][t] = ex2;
        lcur4[1][t] = ex2 + c0;
        lcur4[2][t] = ex2 + c0 + c1;
        lcur4[3][t] = ex2 + c0 + c1 + c2;
        int node = b * 256 + half * 128 + t;
        if (node < n) off[node] = myBase + ex2;
    }
    if (b == ntiles - 1 && half == 0 && t == 0) off[n] = base + cnt;
    __syncthreads();
    // pass 2: scatter from LDS
    for (int i = t; i < cnt; i += 256) {
        u32 key = skey[i];
        int n8 = (int)(key >> 17);
        if ((n8 >> 7) == half) {
            int p = atomicAdd(&lcur4[wv][n8 & 127], 1);
            csr_tgt[myBase + p] = (int)(key & 0x1FFFFu);
        }
    }
}

// ---------------------------------------------------------------------------
// 4) CSR-gather aggregation: r5 body + depth-2 software pipeline on the
//    per-batch tl load (next batch's csr_tgt load issues before current
//    batch's readlane/FMA block -> L2 latency hidden for deg>32 nodes).
// ---------------------------------------------------------------------------
__global__ __launch_bounds__(256) void agg_kernel(
    const u32* __restrict__ Hb, const float* __restrict__ Hs,
    const float* __restrict__ Ht, const int* __restrict__ off,
    const int* __restrict__ csr_tgt, float2* __restrict__ out, int n, int E)
{
    int node = (blockIdx.x * 256 + threadIdx.x) >> 6;
    int L = threadIdx.x & 63;
    if (node >= n) return;
    int lo = off[node], hi = off[node + 1];
    lo = max(0, min(lo, E));
    hi = max(lo, min(hi, E));
    if (hi <= lo) {                            // isolated node: ELU(0)=0
        out[(size_t)node * 64 + L] = {0.f, 0.f};
        return;
    }
    const int h = L >> 4;                      // accumulation head
    const int jSel = L >> 2;                   // duty edge 0..15 (and +16)
    const int hSel = L & 3;                    // duty head
    float4 hs4 = *(const float4*)&Hs[node * HEADS];
    float hsD = hSel == 0 ? hs4.x : hSel == 1 ? hs4.y : hSel == 2 ? hs4.z : hs4.w;
    float ax = 0.f, ay = 0.f, Sd = 0.f;

    int tl = csr_tgt[min(lo + (L & 31), hi - 1)];   // batch-0 tl
    for (int i = lo; i < hi; i += 32) {
        // prefetch next batch's tl (independent of this batch's compute)
        int tln = 0;
        if (i + 32 < hi) tln = csr_tgt[min(i + 32 + (L & 31), hi - 1)];
        int tA = __shfl(tl, jSel);
        int tB = __shfl(tl, jSel + 16);
        float eA = hsD + Ht[tA * HEADS + hSel];
        float eB = hsD + Ht[tB * HEADS + hSel];
        float wA = (i + jSel < hi)
                       ? __expf(fminf(eA > 0.f ? eA : LRELU * eA, 30.f)) : 0.f;
        float wB = (i + jSel + 16 < hi)
                       ? __expf(fminf(eB > 0.f ? eB : LRELU * eB, 30.f)) : 0.f;
        Sd += wA + wB;
        // scalarized gathers: tgt -> SGPR via readlane, saddr-form loads
        u32 bb[32];
        #pragma unroll
        for (int j = 0; j < 32; ++j) {
            int sj = __builtin_amdgcn_readlane(tl, j);
            bb[j] = Hb[((size_t)(u32)sj << 6) + L];
        }
        #pragma unroll
        for (int j = 0; j < 16; ++j) {
            float wj = __shfl(wA, (j << 2) | h);
            float2 f = up2(bb[j]);
            ax += wj * f.x;
            ay += wj * f.y;
        }
        #pragma unroll
        for (int j = 0; j < 16; ++j) {
            float wj = __shfl(wB, (j << 2) | h);
            float2 f = up2(bb[j + 16]);
            ax += wj * f.x;
            ay += wj * f.y;
        }
        tl = tln;
    }
    float S = 0.f;
    #pragma unroll
    for (int j = 0; j < 16; ++j) S += __shfl(Sd, (j << 2) | h);
    float inv = 1.f / (S + 1e-8f);
    float ox = ax * inv, oy = ay * inv;
    ox = ox > 0.f ? ox : (__expf(ox) - 1.f);
    oy = oy > 0.f ? oy : (__expf(oy) - 1.f);
    out[(size_t)node * 64 + L] = {ox, oy};
}

// ---------------------------------------------------------------------------
extern "C" void kernel_launch(void* const* d_in, const int* in_sizes, int n_in,
                              void* d_out, int out_size, void* d_ws, size_t ws_size,
                              hipStream_t stream) {
    const float* X  = (const float*)d_in[0];   // fp32
    const int*   EI = (const int*)d_in[1];     // int32[2E] block layout
    const float* W  = (const float*)d_in[2];   // fp32 row-major
    const float* AL = (const float*)d_in[3];
    const float* AR = (const float*)d_in[4];
    const int n = in_sizes[0] / DIM;      // 50000
    const int E = in_sizes[1] / 2;        // 1600000
    const int ntiles = (n + 255) / 256;   // 196 buckets

    char* ws = (char*)d_ws;
    size_t o = 0;
    auto alloc = [&](size_t bytes) -> void* {
        o = (o + 255) & ~(size_t)255;
        void* p = ws + o;
        o += bytes;
        return p;
    };
    int*   bcur    = (int*)alloc(256 * 4);
    u16*   Wt      = (u16*)alloc((size_t)DIM * DIM * 2);      // 32 KB
    int*   off     = (int*)alloc((size_t)(n + 1) * 4);
    float* Hs      = (float*)alloc((size_t)n * HEADS * 4);
    float* Ht      = (float*)alloc((size_t)n * HEADS * 4);
    int*   csr_tgt = (int*)alloc((size_t)E * 4);
    u32*   part    = (u32*)alloc((size_t)ntiles * CAP * 4);   // 7.2 MB
    u32*   Hb      = (u32*)alloc((size_t)n * 64 * 4);

    const int PB = (E + PT - 1) / PT;     // 391 partition blocks
    const int JB = (n + 63) / 64;         // 782 proj blocks

    prep_kernel<<<8, 256, 0, stream>>>(W, Wt, bcur);
    fused_pp_kernel<<<PB + JB, 256, 0, stream>>>(
        X, Wt, AL, AR, Hb, Hs, Ht, EI, bcur, part, n, E, PB);
    csrfill_kernel<<<ntiles * 2, 256, 0, stream>>>(part, bcur, off, csr_tgt, n, ntiles);
    agg_kernel<<<(n + 3) / 4, 256, 0, stream>>>(
        Hb, Hs, Ht, off, csr_tgt, (float2*)d_out, n, E);
}